// Round 4
// baseline (1769.767 us; speedup 1.0000x reference)
//
#include <hip/hip_runtime.h>
#include <hip/hip_bf16.h>

// Exact-match requirement for FPS/KNN index selection: no FMA contraction,
// replicate numpy fp32 expression order. Conv layers use explicit fmaf.
#pragma clang fp contract(off)

#define NPTS 8192
#define NS   1024
#define NB   2
#define NC   29
#define NK   16

// ---------------- workspace layout (bytes) ----------------
// nx      float[6144]    @ 8192
// knn     int[32768]     @ 32768
// w0t     float[73728]   @ 163840
// bias0   float[64]      @ 458752
// w1t     float[36864]   @ 459008
// w2t     float[73728]   @ 606464
// w3t     float[65536]   @ 901376

// ---------------- weight prep: transpose to [K][tap][O], fold ones-channels into bias0 ----------------
__global__ __launch_bounds__(256) void prep_kernel(
    const float* __restrict__ w0, const float* __restrict__ w1,
    const float* __restrict__ w2, const float* __restrict__ w3,
    float* __restrict__ w0t, float* __restrict__ w1t,
    float* __restrict__ w2t, float* __restrict__ w3t,
    float* __restrict__ bias0)
{
    int i = blockIdx.x * 256 + threadIdx.x;
    int n = gridDim.x * 256;
    for (int e = i; e < 73728; e += n) {
        int o = e & 63, r = e >> 6, tap = r % 9, ic2 = r / 9;
        int ic = ((ic2 >> 5) << 6) + (ic2 & 31);
        w0t[e] = w0[(o * 256 + ic) * 9 + tap];
    }
    for (int e = i; e < 36864; e += n) {
        int o = e & 63, r = e >> 6, tap = r % 9, ic = r / 9;
        w1t[e] = w1[(o * 64 + ic) * 9 + tap];
    }
    for (int e = i; e < 73728; e += n) {
        int o = e & 127, r = e >> 7, tap = r % 9, ic = r / 9;
        w2t[e] = w2[(o * 64 + ic) * 9 + tap];
    }
    for (int e = i; e < 65536; e += n) {
        int o = e & 127, r = e >> 7, tap = r & 3, ic = r >> 2;
        w3t[e] = w3[(o * 128 + ic) * 4 + tap];
    }
    if (i < 64) {
        float sum = 0.0f;
        for (int q = 0; q < 4; ++q)
            for (int c = 0; c < 32; ++c)
                for (int t = 0; t < 9; ++t)
                    sum += w0[(i * 256 + q * 64 + 32 + c) * 9 + t];
        bias0[i] = sum;
    }
}

// ---------------- FPS: one 1024-thread block per batch, 8 pts/thread in regs ----------------
// Arrays = 32 VGPRs -> guaranteed register-resident (R3's 32/thread spilled at VGPR=104).
// Per iter: wave-reduce packed u64 key, ONE barrier, all threads combine 16 partials
// (broadcast LDS reads) and re-fetch centroid from L2.
__global__ __launch_bounds__(1024) void fps_kernel(
    const float* __restrict__ xyz,
    float* __restrict__ nx_ws, float* __restrict__ out)
{
    int b = blockIdx.x;
    int tid = threadIdx.x;
    const float* X = xyz + b * 3 * NPTS;

    __shared__ unsigned long long s_part[2][16];
    __shared__ int s_idx[NS];

    float px[8], py[8], pz[8], dist[8];
#pragma unroll
    for (int i = 0; i < 8; ++i) {
        int gi = i * 1024 + tid;                // coalesced: lane-contiguous
        px[i] = X[gi];
        py[i] = X[NPTS + gi];
        pz[i] = X[2 * NPTS + gi];
        dist[i] = 1e10f;
    }

    float* out_fps = out + 268288 + b * NS;
    if (tid == 0) { s_idx[0] = 0; out_fps[0] = 0.0f; }

    float cx = X[0], cy = X[NPTS], cz = X[2 * NPTS];
    int wv = tid >> 6, lane = tid & 63;

    for (int it = 1; it < NS; ++it) {
        float bv = -1.0f; int bi = 0;
#pragma unroll
        for (int i = 0; i < 8; ++i) {
            float dx = px[i] - cx, dy = py[i] - cy, dz = pz[i] - cz;
            float d = (dx * dx + dy * dy) + dz * dz;   // numpy order, no fma
            float nd = fminf(dist[i], d);
            dist[i] = nd;
            if (nd > bv) { bv = nd; bi = i; }          // strict > keeps earliest
        }
        int gbi = (bi << 10) + tid;                     // global index, increasing in bi
        // non-negative float bits are order-isomorphic to uint; tie -> max(8191-gbi) = min gbi
        unsigned long long key =
            ((unsigned long long)__float_as_uint(bv) << 32) | (unsigned)(8191 - gbi);
#pragma unroll
        for (int off = 32; off > 0; off >>= 1) {
            unsigned long long ok = __shfl_down(key, off, 64);
            if (ok > key) key = ok;
        }
        if (lane == 0) s_part[it & 1][wv] = key;
        __syncthreads();
        unsigned long long best = s_part[it & 1][0];
#pragma unroll
        for (int w = 1; w < 16; ++w) {
            unsigned long long k = s_part[it & 1][w];
            if (k > best) best = k;
        }
        int idx = 8191 - (int)(unsigned)(best & 0xffffffffULL);
        if (tid == 0) { out_fps[it] = (float)idx; s_idx[it] = idx; }
        // centroid re-fetch: same-address broadcast load, L2-resident (96 KB input)
        cx = X[idx]; cy = X[NPTS + idx]; cz = X[2 * NPTS + idx];
    }
    __syncthreads();
    // gather new_xyz (NS == blockDim)
    {
        int j = s_idx[tid];
        float x = X[j], y = X[NPTS + j], z = X[2 * NPTS + j];
        nx_ws[(b * 3 + 0) * NS + tid] = x; out[(b * 3 + 0) * NS + tid] = x;
        nx_ws[(b * 3 + 1) * NS + tid] = y; out[(b * 3 + 1) * NS + tid] = y;
        nx_ws[(b * 3 + 2) * NS + tid] = z; out[(b * 3 + 2) * NS + tid] = z;
    }
}

// ---------------- KNN: one wave per query ----------------
__global__ __launch_bounds__(256) void knn_kernel(
    const float* __restrict__ nx_ws, int* __restrict__ knn_ws)
{
    int q = blockIdx.x * 4 + (threadIdx.x >> 6);
    int lane = threadIdx.x & 63;
    int b = q >> 10, s = q & 1023;
    const float* P = nx_ws + b * 3 * NS;
    float qx = P[s], qy = P[NS + s], qz = P[2 * NS + s];
    float sqq = (qx * qx + qy * qy) + qz * qz;
    int base_j = lane * 16;
    float d2[16];
    {
        const float4* x4 = (const float4*)(P + base_j);
        const float4* y4 = (const float4*)(P + NS + base_j);
        const float4* z4 = (const float4*)(P + 2 * NS + base_j);
#pragma unroll
        for (int t = 0; t < 4; ++t) {
            float4 xv = x4[t], yv = y4[t], zv = z4[t];
            float xs[4] = { xv.x, xv.y, xv.z, xv.w };
            float ys[4] = { yv.x, yv.y, yv.z, yv.w };
            float zs[4] = { zv.x, zv.y, zv.z, zv.w };
#pragma unroll
            for (int e = 0; e < 4; ++e) {
                float xj = xs[e], yj = ys[e], zj = zs[e];
                float sqj = (xj * xj + yj * yj) + zj * zj;
                float dot = (qx * xj + qy * yj) + qz * zj;
                d2[t * 4 + e] = (sqq + sqj) - 2.0f * dot;   // numpy order
            }
        }
    }
    for (int r = 0; r < NK; ++r) {
        float lv = 3.0e38f; int li = 0;
#pragma unroll
        for (int i = 0; i < 16; ++i) { if (d2[i] < lv) { lv = d2[i]; li = i; } } // strict < keeps earliest
        int gj = base_j + li;
#pragma unroll
        for (int off = 32; off > 0; off >>= 1) {
            float ov = __shfl_xor(lv, off, 64);
            int   oj = __shfl_xor(gj, off, 64);
            if (ov < lv || (ov == lv && oj < gj)) { lv = ov; gj = oj; }
        }
        if (lane == 0) knn_ws[q * NK + r] = gj;
        if ((gj >> 4) == lane) {
            int li2 = gj & 15;
#pragma unroll
            for (int i = 0; i < 16; ++i) if (i == li2) d2[i] = 3.0e38f;
        }
    }
}

// ---------------- conv0 inner helper (positions compile-time per parity of g) ----------------
template<int GODD>
__device__ __forceinline__ void conv0_accum(
    const float* __restrict__ x0r, const float* __restrict__ wbase, float acc[9])
{
    for (int ic2 = 0; ic2 < 128; ++ic2) {
        const float4* x4 = (const float4*)(x0r + ic2 * 64);
        float rr[32];
#pragma unroll
        for (int j = 0; j < 4; ++j) {
            float4 t0 = x4[j * 2], t1 = x4[j * 2 + 1];
            rr[j*8+0]=t0.x; rr[j*8+1]=t0.y; rr[j*8+2]=t0.z; rr[j*8+3]=t0.w;
            rr[j*8+4]=t1.x; rr[j*8+5]=t1.y; rr[j*8+6]=t1.z; rr[j*8+7]=t1.w;
        }
        float w[9];
#pragma unroll
        for (int t = 0; t < 9; ++t) w[t] = wbase[(ic2 * 9 + t) * 64];
#pragma unroll
        for (int pp = 0; pp < 9; ++pp) {
            const int ly = GODD ? (pp < 3 ? 0 : 1) : (pp < 6 ? 0 : 1);
            const int xx = GODD ? (pp < 3 ? pp + 3 : pp - 3) : (pp < 6 ? pp : pp - 6);
#pragma unroll
            for (int ky = 0; ky < 3; ++ky)
#pragma unroll
                for (int kx = 0; kx < 3; ++kx)
                    acc[pp] = __builtin_fmaf(w[ky * 3 + kx], rr[(ly + ky) * 8 + xx + kx], acc[pp]);
        }
    }
}

// ---------------- per-sample conv chain ----------------
__global__ __launch_bounds__(256) void conv_kernel(
    const float* __restrict__ feats, const float* __restrict__ nx_ws,
    const int* __restrict__ knn_ws,
    const float* __restrict__ w0t, const float* __restrict__ bias0,
    const float* __restrict__ w1t, const float* __restrict__ w2t,
    const float* __restrict__ w3t, float* __restrict__ out)
{
    __shared__ float s_fg[512];       // [d][k]
    __shared__ int   s_ni[16];
    __shared__ float s_x0[8192];      // [ic2][u*8+v], outer channels only
    __shared__ float s_a1[64 * 36];
    __shared__ float s_a2[64 * 16];
    __shared__ float s_a3[128 * 4];

    int bs = blockIdx.x, b = bs >> 10, s = bs & 1023;
    int tid = threadIdx.x;
    if (tid < 16) s_ni[tid] = knn_ws[bs * NK + tid];
    __syncthreads();
    const float* P = nx_ws + b * 3 * NS;
#pragma unroll
    for (int e = tid; e < 512; e += 256) {
        int d = e >> 4, k = e & 15; int j = s_ni[k];
        float v = (d < 3) ? (P[d * NS + j] - P[d * NS + s])
                          : feats[(b * NC + (d - 3)) * NPTS + j];
        s_fg[e] = v;
    }
    __syncthreads();
    for (int e = tid; e < 8192; e += 256) {
        int ic2 = e >> 6, pos = e & 63, u = pos >> 3, v = pos & 7;
        int q = ic2 >> 5, ch = ic2 & 31;
        int ro = q & 1, co = ((q + 1) >> 1) & 1;    // tl,br,tr,bl
        s_x0[e] = s_fg[ch * 16 + 2 * u + ro] * s_fg[ch * 16 + 2 * v + co];
    }
    __syncthreads();

    int o = tid & 63, g = tid >> 6;
    { // conv0: 64 out-ch x 6x6, K = 128x9 (+ bias from ones-channels)
        int r0 = g + (g >> 1);
        float acc[9];
        float bz = bias0[o];
#pragma unroll
        for (int p = 0; p < 9; ++p) acc[p] = bz;
        const float* x0r = s_x0 + r0 * 8;
        const float* wb = w0t + o;
        if (g & 1) conv0_accum<1>(x0r, wb, acc);
        else       conv0_accum<0>(x0r, wb, acc);
#pragma unroll
        for (int pp = 0; pp < 9; ++pp) s_a1[o * 36 + g * 9 + pp] = fmaxf(acc[pp], 0.0f);
    }
    __syncthreads();
    { // conv1: 64 x 4x4, K = 64x9 ; y = g
        float a[4] = {0, 0, 0, 0};
        const float* wb = w1t + o;
        for (int ic = 0; ic < 64; ++ic) {
            const float2* ar2 = (const float2*)(s_a1 + ic * 36 + g * 6);
            float r[18];
#pragma unroll
            for (int t = 0; t < 9; ++t) { float2 tv = ar2[t]; r[t*2] = tv.x; r[t*2+1] = tv.y; }
            float w[9];
#pragma unroll
            for (int t = 0; t < 9; ++t) w[t] = wb[(ic * 9 + t) * 64];
#pragma unroll
            for (int x = 0; x < 4; ++x)
#pragma unroll
                for (int ky = 0; ky < 3; ++ky)
#pragma unroll
                    for (int kx = 0; kx < 3; ++kx)
                        a[x] = __builtin_fmaf(w[ky * 3 + kx], r[ky * 6 + x + kx], a[x]);
        }
#pragma unroll
        for (int x = 0; x < 4; ++x) s_a2[o * 16 + g * 4 + x] = fmaxf(a[x], 0.0f);
    }
    __syncthreads();
    { // conv2: 128 x 2x2, K = 64x9 ; y = g2
        int o2 = tid & 127, g2 = tid >> 7;
        float a[2] = {0, 0};
        const float* wb = w2t + o2;
        for (int ic = 0; ic < 64; ++ic) {
            const float4* ar4 = (const float4*)(s_a2 + ic * 16 + g2 * 4);
            float r[12];
#pragma unroll
            for (int t = 0; t < 3; ++t) { float4 tv = ar4[t]; r[t*4]=tv.x; r[t*4+1]=tv.y; r[t*4+2]=tv.z; r[t*4+3]=tv.w; }
            float w[9];
#pragma unroll
            for (int t = 0; t < 9; ++t) w[t] = wb[(ic * 9 + t) * 128];
#pragma unroll
            for (int x = 0; x < 2; ++x)
#pragma unroll
                for (int ky = 0; ky < 3; ++ky)
#pragma unroll
                    for (int kx = 0; kx < 3; ++kx)
                        a[x] = __builtin_fmaf(w[ky * 3 + kx], r[ky * 4 + x + kx], a[x]);
        }
#pragma unroll
        for (int x = 0; x < 2; ++x) s_a3[o2 * 4 + g2 * 2 + x] = fmaxf(a[x], 0.0f);
    }
    __syncthreads();
    // conv3: 128 out, K = 128x4 -> 1x1, relu, write new_points
    if (tid < 128) {
        float acc = 0.0f;
        const float* wb = w3t + tid;
        for (int ic = 0; ic < 128; ++ic) {
            float4 av = *(const float4*)(s_a3 + ic * 4);
            float wa = wb[(ic * 4 + 0) * 128];
            float wbv = wb[(ic * 4 + 1) * 128];
            float wc = wb[(ic * 4 + 2) * 128];
            float wd = wb[(ic * 4 + 3) * 128];
            acc = __builtin_fmaf(wa, av.x, acc);
            acc = __builtin_fmaf(wbv, av.y, acc);
            acc = __builtin_fmaf(wc, av.z, acc);
            acc = __builtin_fmaf(wd, av.w, acc);
        }
        out[6144 + (b * 128 + tid) * NS + s] = fmaxf(acc, 0.0f);
    }
}

extern "C" void kernel_launch(void* const* d_in, const int* in_sizes, int n_in,
                              void* d_out, int out_size, void* d_ws, size_t ws_size,
                              hipStream_t stream) {
    const float* xyz   = (const float*)d_in[0];
    const float* feats = (const float*)d_in[1];
    const float* w0    = (const float*)d_in[2];
    const float* w1    = (const float*)d_in[3];
    const float* w2    = (const float*)d_in[4];
    const float* w3    = (const float*)d_in[5];
    float* out = (float*)d_out;

    char* ws = (char*)d_ws;
    float* nx_ws  = (float*)(ws + 8192);
    int*   knn_ws = (int*)(ws + 32768);
    float* w0t    = (float*)(ws + 163840);
    float* bias0  = (float*)(ws + 458752);
    float* w1t    = (float*)(ws + 459008);
    float* w2t    = (float*)(ws + 606464);
    float* w3t    = (float*)(ws + 901376);

    prep_kernel<<<128, 256, 0, stream>>>(w0, w1, w2, w3, w0t, w1t, w2t, w3t, bias0);
    fps_kernel<<<NB, 1024, 0, stream>>>(xyz, nx_ws, out);
    knn_kernel<<<(NB * NS) / 4, 256, 0, stream>>>(nx_ws, knn_ws);
    conv_kernel<<<NB * NS, 256, 0, stream>>>(feats, nx_ws, knn_ws, w0t, bias0, w1t, w2t, w3t, out);
}

// Round 5
// 1440.836 us; speedup vs baseline: 1.2283x; 1.2283x over previous
//
#include <hip/hip_runtime.h>
#include <hip/hip_bf16.h>

// Exact-match requirement for FPS/KNN index selection: no FMA contraction,
// replicate numpy fp32 expression order. Conv layers use explicit fmaf.
#pragma clang fp contract(off)

#define NPTS 8192
#define NS   1024
#define NB   2
#define NC   29
#define NK   16

// ---------------- workspace layout (bytes) ----------------
// nx      float[6144]    @ 8192
// knn     int[32768]     @ 32768
// w0t     float[73728]   @ 163840
// bias0   float[64]      @ 458752
// w1t     float[36864]   @ 459008
// w2t     float[73728]   @ 606464
// w3t     float[65536]   @ 901376

// ---------------- weight prep: transpose to [K][tap][O], fold ones-channels into bias0 ----------------
__global__ __launch_bounds__(256) void prep_kernel(
    const float* __restrict__ w0, const float* __restrict__ w1,
    const float* __restrict__ w2, const float* __restrict__ w3,
    float* __restrict__ w0t, float* __restrict__ w1t,
    float* __restrict__ w2t, float* __restrict__ w3t,
    float* __restrict__ bias0)
{
    int i = blockIdx.x * 256 + threadIdx.x;
    int n = gridDim.x * 256;
    for (int e = i; e < 73728; e += n) {
        int o = e & 63, r = e >> 6, tap = r % 9, ic2 = r / 9;
        int ic = ((ic2 >> 5) << 6) + (ic2 & 31);
        w0t[e] = w0[(o * 256 + ic) * 9 + tap];
    }
    for (int e = i; e < 36864; e += n) {
        int o = e & 63, r = e >> 6, tap = r % 9, ic = r / 9;
        w1t[e] = w1[(o * 64 + ic) * 9 + tap];
    }
    for (int e = i; e < 73728; e += n) {
        int o = e & 127, r = e >> 7, tap = r % 9, ic = r / 9;
        w2t[e] = w2[(o * 64 + ic) * 9 + tap];
    }
    for (int e = i; e < 65536; e += n) {
        int o = e & 127, r = e >> 7, tap = r & 3, ic = r >> 2;
        w3t[e] = w3[(o * 128 + ic) * 4 + tap];
    }
    if (i < 64) {
        float sum = 0.0f;
        for (int q = 0; q < 4; ++q)
            for (int c = 0; c < 32; ++c)
                for (int t = 0; t < 9; ++t)
                    sum += w0[(i * 256 + q * 64 + 32 + c) * 9 + t];
        bias0[i] = sum;
    }
}

// DPP wave64 max for non-negative floats (bound_ctrl zeros are identity for max).
// row_shr 1/2/4/8 -> lane15 of each 16-row holds row max; row_bcast15 (rows 1,3)
// then row_bcast31 (rows 2,3) -> lane 63 holds full wave max.
__device__ __forceinline__ float wave_max_nonneg(float x) {
    int v = __float_as_int(x);
    int t;
    t = __builtin_amdgcn_update_dpp(0, v, 0x111, 0xf, 0xf, true);
    v = __float_as_int(fmaxf(__int_as_float(v), __int_as_float(t)));
    t = __builtin_amdgcn_update_dpp(0, v, 0x112, 0xf, 0xf, true);
    v = __float_as_int(fmaxf(__int_as_float(v), __int_as_float(t)));
    t = __builtin_amdgcn_update_dpp(0, v, 0x114, 0xf, 0xf, true);
    v = __float_as_int(fmaxf(__int_as_float(v), __int_as_float(t)));
    t = __builtin_amdgcn_update_dpp(0, v, 0x118, 0xf, 0xf, true);
    v = __float_as_int(fmaxf(__int_as_float(v), __int_as_float(t)));
    t = __builtin_amdgcn_update_dpp(0, v, 0x142, 0xa, 0xf, true);
    v = __float_as_int(fmaxf(__int_as_float(v), __int_as_float(t)));
    t = __builtin_amdgcn_update_dpp(0, v, 0x143, 0xc, 0xf, true);
    v = __float_as_int(fmaxf(__int_as_float(v), __int_as_float(t)));
    return __int_as_float(__builtin_amdgcn_readlane(v, 63));
}

// ---------------- FPS: one 1024-thread block per batch, 8 pts/thread in regs ----------------
// Value-only update (no per-point argmax bookkeeping), DPP wave max, one LDS
// atomicMax(u32 float-bits) per wave, winner threads resolve exact numpy argmax
// index via LDS atomicMin on the global point index. Two barriers per iter.
__global__ __launch_bounds__(1024) void fps_kernel(
    const float* __restrict__ xyz,
    float* __restrict__ nx_ws, float* __restrict__ out)
{
    int b = blockIdx.x;
    int tid = threadIdx.x;
    const float* X = xyz + b * 3 * NPTS;

    __shared__ unsigned s_max[2];
    __shared__ int s_gi[2];
    __shared__ int s_idx[NS];

    float px[8], py[8], pz[8], dist[8];
#pragma unroll
    for (int i = 0; i < 8; ++i) {
        int gi = i * 1024 + tid;                // point index == (i<<10)+tid
        px[i] = X[gi];
        py[i] = X[NPTS + gi];
        pz[i] = X[2 * NPTS + gi];
        dist[i] = 1e10f;
    }

    float* out_fps = out + 268288 + b * NS;
    if (tid == 0) {
        s_idx[0] = 0; out_fps[0] = 0.0f;
        s_max[0] = 0u; s_max[1] = 0u;
        s_gi[0] = 0x7fffffff; s_gi[1] = 0x7fffffff;
    }
    __syncthreads();

    float cx = X[0], cy = X[NPTS], cz = X[2 * NPTS];
    int lane = tid & 63;

    for (int it = 1; it < NS; ++it) {
        int par = it & 1;
        // ---- update dists (exact numpy order, no fma) ----
#pragma unroll
        for (int i = 0; i < 8; ++i) {
            float dx = px[i] - cx, dy = py[i] - cy, dz = pz[i] - cz;
            float d = (dx * dx + dy * dy) + dz * dz;
            dist[i] = fminf(dist[i], d);
        }
        // ---- local value max (tree, 7 ops) ----
        float m0 = fmaxf(dist[0], dist[1]);
        float m1 = fmaxf(dist[2], dist[3]);
        float m2 = fmaxf(dist[4], dist[5]);
        float m3 = fmaxf(dist[6], dist[7]);
        float m4 = fmaxf(m0, m1);
        float m5 = fmaxf(m2, m3);
        float bv = fmaxf(m4, m5);
        // ---- wave max via DPP, one atomic per wave ----
        float wm = wave_max_nonneg(bv);
        if (lane == 0) atomicMax(&s_max[par], __float_as_uint(wm));
        __syncthreads();
        float gbv = __uint_as_float(s_max[par]);
        if (tid == 0) { s_max[par ^ 1] = 0u; s_gi[par ^ 1] = 0x7fffffff; }
        // ---- winners resolve exact first-index argmax ----
        if (bv == gbv) {
            int gi = 0;
#pragma unroll
            for (int i = 7; i >= 0; --i)
                if (dist[i] == gbv) gi = (i << 10) + tid;   // ends at smallest i
            atomicMin(&s_gi[par], gi);
        }
        __syncthreads();
        int idx = s_gi[par];
        if (tid == 0) { out_fps[it] = (float)idx; s_idx[it] = idx; }
        // centroid re-fetch: same-address broadcast load, L2-resident (96 KB input)
        cx = X[idx]; cy = X[NPTS + idx]; cz = X[2 * NPTS + idx];
    }
    __syncthreads();
    // gather new_xyz (NS == blockDim)
    {
        int j = s_idx[tid];
        float x = X[j], y = X[NPTS + j], z = X[2 * NPTS + j];
        nx_ws[(b * 3 + 0) * NS + tid] = x; out[(b * 3 + 0) * NS + tid] = x;
        nx_ws[(b * 3 + 1) * NS + tid] = y; out[(b * 3 + 1) * NS + tid] = y;
        nx_ws[(b * 3 + 2) * NS + tid] = z; out[(b * 3 + 2) * NS + tid] = z;
    }
}

// ---------------- KNN: one wave per query ----------------
__global__ __launch_bounds__(256) void knn_kernel(
    const float* __restrict__ nx_ws, int* __restrict__ knn_ws)
{
    int q = blockIdx.x * 4 + (threadIdx.x >> 6);
    int lane = threadIdx.x & 63;
    int b = q >> 10, s = q & 1023;
    const float* P = nx_ws + b * 3 * NS;
    float qx = P[s], qy = P[NS + s], qz = P[2 * NS + s];
    float sqq = (qx * qx + qy * qy) + qz * qz;
    int base_j = lane * 16;
    float d2[16];
    {
        const float4* x4 = (const float4*)(P + base_j);
        const float4* y4 = (const float4*)(P + NS + base_j);
        const float4* z4 = (const float4*)(P + 2 * NS + base_j);
#pragma unroll
        for (int t = 0; t < 4; ++t) {
            float4 xv = x4[t], yv = y4[t], zv = z4[t];
            float xs[4] = { xv.x, xv.y, xv.z, xv.w };
            float ys[4] = { yv.x, yv.y, yv.z, yv.w };
            float zs[4] = { zv.x, zv.y, zv.z, zv.w };
#pragma unroll
            for (int e = 0; e < 4; ++e) {
                float xj = xs[e], yj = ys[e], zj = zs[e];
                float sqj = (xj * xj + yj * yj) + zj * zj;
                float dot = (qx * xj + qy * yj) + qz * zj;
                d2[t * 4 + e] = (sqq + sqj) - 2.0f * dot;   // numpy order
            }
        }
    }
    for (int r = 0; r < NK; ++r) {
        float lv = 3.0e38f; int li = 0;
#pragma unroll
        for (int i = 0; i < 16; ++i) { if (d2[i] < lv) { lv = d2[i]; li = i; } } // strict < keeps earliest
        int gj = base_j + li;
#pragma unroll
        for (int off = 32; off > 0; off >>= 1) {
            float ov = __shfl_xor(lv, off, 64);
            int   oj = __shfl_xor(gj, off, 64);
            if (ov < lv || (ov == lv && oj < gj)) { lv = ov; gj = oj; }
        }
        if (lane == 0) knn_ws[q * NK + r] = gj;
        if ((gj >> 4) == lane) {
            int li2 = gj & 15;
#pragma unroll
            for (int i = 0; i < 16; ++i) if (i == li2) d2[i] = 3.0e38f;
        }
    }
}

// ---------------- conv0 inner helper (positions compile-time per parity of g) ----------------
template<int GODD>
__device__ __forceinline__ void conv0_accum(
    const float* __restrict__ x0r, const float* __restrict__ wbase, float acc[9])
{
    for (int ic2 = 0; ic2 < 128; ++ic2) {
        const float4* x4 = (const float4*)(x0r + ic2 * 64);
        float rr[32];
#pragma unroll
        for (int j = 0; j < 4; ++j) {
            float4 t0 = x4[j * 2], t1 = x4[j * 2 + 1];
            rr[j*8+0]=t0.x; rr[j*8+1]=t0.y; rr[j*8+2]=t0.z; rr[j*8+3]=t0.w;
            rr[j*8+4]=t1.x; rr[j*8+5]=t1.y; rr[j*8+6]=t1.z; rr[j*8+7]=t1.w;
        }
        float w[9];
#pragma unroll
        for (int t = 0; t < 9; ++t) w[t] = wbase[(ic2 * 9 + t) * 64];
#pragma unroll
        for (int pp = 0; pp < 9; ++pp) {
            const int ly = GODD ? (pp < 3 ? 0 : 1) : (pp < 6 ? 0 : 1);
            const int xx = GODD ? (pp < 3 ? pp + 3 : pp - 3) : (pp < 6 ? pp : pp - 6);
#pragma unroll
            for (int ky = 0; ky < 3; ++ky)
#pragma unroll
                for (int kx = 0; kx < 3; ++kx)
                    acc[pp] = __builtin_fmaf(w[ky * 3 + kx], rr[(ly + ky) * 8 + xx + kx], acc[pp]);
        }
    }
}

// ---------------- per-sample conv chain ----------------
__global__ __launch_bounds__(256) void conv_kernel(
    const float* __restrict__ feats, const float* __restrict__ nx_ws,
    const int* __restrict__ knn_ws,
    const float* __restrict__ w0t, const float* __restrict__ bias0,
    const float* __restrict__ w1t, const float* __restrict__ w2t,
    const float* __restrict__ w3t, float* __restrict__ out)
{
    __shared__ float s_fg[512];       // [d][k]
    __shared__ int   s_ni[16];
    __shared__ float s_x0[8192];      // [ic2][u*8+v], outer channels only
    __shared__ float s_a1[64 * 36];
    __shared__ float s_a2[64 * 16];
    __shared__ float s_a3[128 * 4];

    int bs = blockIdx.x, b = bs >> 10, s = bs & 1023;
    int tid = threadIdx.x;
    if (tid < 16) s_ni[tid] = knn_ws[bs * NK + tid];
    __syncthreads();
    const float* P = nx_ws + b * 3 * NS;
#pragma unroll
    for (int e = tid; e < 512; e += 256) {
        int d = e >> 4, k = e & 15; int j = s_ni[k];
        float v = (d < 3) ? (P[d * NS + j] - P[d * NS + s])
                          : feats[(b * NC + (d - 3)) * NPTS + j];
        s_fg[e] = v;
    }
    __syncthreads();
    for (int e = tid; e < 8192; e += 256) {
        int ic2 = e >> 6, pos = e & 63, u = pos >> 3, v = pos & 7;
        int q = ic2 >> 5, ch = ic2 & 31;
        int ro = q & 1, co = ((q + 1) >> 1) & 1;    // tl,br,tr,bl
        s_x0[e] = s_fg[ch * 16 + 2 * u + ro] * s_fg[ch * 16 + 2 * v + co];
    }
    __syncthreads();

    int o = tid & 63, g = tid >> 6;
    { // conv0: 64 out-ch x 6x6, K = 128x9 (+ bias from ones-channels)
        int r0 = g + (g >> 1);
        float acc[9];
        float bz = bias0[o];
#pragma unroll
        for (int p = 0; p < 9; ++p) acc[p] = bz;
        const float* x0r = s_x0 + r0 * 8;
        const float* wb = w0t + o;
        if (g & 1) conv0_accum<1>(x0r, wb, acc);
        else       conv0_accum<0>(x0r, wb, acc);
#pragma unroll
        for (int pp = 0; pp < 9; ++pp) s_a1[o * 36 + g * 9 + pp] = fmaxf(acc[pp], 0.0f);
    }
    __syncthreads();
    { // conv1: 64 x 4x4, K = 64x9 ; y = g
        float a[4] = {0, 0, 0, 0};
        const float* wb = w1t + o;
        for (int ic = 0; ic < 64; ++ic) {
            const float2* ar2 = (const float2*)(s_a1 + ic * 36 + g * 6);
            float r[18];
#pragma unroll
            for (int t = 0; t < 9; ++t) { float2 tv = ar2[t]; r[t*2] = tv.x; r[t*2+1] = tv.y; }
            float w[9];
#pragma unroll
            for (int t = 0; t < 9; ++t) w[t] = wb[(ic * 9 + t) * 64];
#pragma unroll
            for (int x = 0; x < 4; ++x)
#pragma unroll
                for (int ky = 0; ky < 3; ++ky)
#pragma unroll
                    for (int kx = 0; kx < 3; ++kx)
                        a[x] = __builtin_fmaf(w[ky * 3 + kx], r[ky * 6 + x + kx], a[x]);
        }
#pragma unroll
        for (int x = 0; x < 4; ++x) s_a2[o * 16 + g * 4 + x] = fmaxf(a[x], 0.0f);
    }
    __syncthreads();
    { // conv2: 128 x 2x2, K = 64x9 ; y = g2
        int o2 = tid & 127, g2 = tid >> 7;
        float a[2] = {0, 0};
        const float* wb = w2t + o2;
        for (int ic = 0; ic < 64; ++ic) {
            const float4* ar4 = (const float4*)(s_a2 + ic * 16 + g2 * 4);
            float r[12];
#pragma unroll
            for (int t = 0; t < 3; ++t) { float4 tv = ar4[t]; r[t*4]=tv.x; r[t*4+1]=tv.y; r[t*4+2]=tv.z; r[t*4+3]=tv.w; }
            float w[9];
#pragma unroll
            for (int t = 0; t < 9; ++t) w[t] = wb[(ic * 9 + t) * 128];
#pragma unroll
            for (int x = 0; x < 2; ++x)
#pragma unroll
                for (int ky = 0; ky < 3; ++ky)
#pragma unroll
                    for (int kx = 0; kx < 3; ++kx)
                        a[x] = __builtin_fmaf(w[ky * 3 + kx], r[ky * 4 + x + kx], a[x]);
        }
#pragma unroll
        for (int x = 0; x < 2; ++x) s_a3[o2 * 4 + g2 * 2 + x] = fmaxf(a[x], 0.0f);
    }
    __syncthreads();
    // conv3: 128 out, K = 128x4 -> 1x1, relu, write new_points
    if (tid < 128) {
        float acc = 0.0f;
        const float* wb = w3t + tid;
        for (int ic = 0; ic < 128; ++ic) {
            float4 av = *(const float4*)(s_a3 + ic * 4);
            float wa = wb[(ic * 4 + 0) * 128];
            float wbv = wb[(ic * 4 + 1) * 128];
            float wc = wb[(ic * 4 + 2) * 128];
            float wd = wb[(ic * 4 + 3) * 128];
            acc = __builtin_fmaf(wa, av.x, acc);
            acc = __builtin_fmaf(wbv, av.y, acc);
            acc = __builtin_fmaf(wc, av.z, acc);
            acc = __builtin_fmaf(wd, av.w, acc);
        }
        out[6144 + (b * 128 + tid) * NS + s] = fmaxf(acc, 0.0f);
    }
}

extern "C" void kernel_launch(void* const* d_in, const int* in_sizes, int n_in,
                              void* d_out, int out_size, void* d_ws, size_t ws_size,
                              hipStream_t stream) {
    const float* xyz   = (const float*)d_in[0];
    const float* feats = (const float*)d_in[1];
    const float* w0    = (const float*)d_in[2];
    const float* w1    = (const float*)d_in[3];
    const float* w2    = (const float*)d_in[4];
    const float* w3    = (const float*)d_in[5];
    float* out = (float*)d_out;

    char* ws = (char*)d_ws;
    float* nx_ws  = (float*)(ws + 8192);
    int*   knn_ws = (int*)(ws + 32768);
    float* w0t    = (float*)(ws + 163840);
    float* bias0  = (float*)(ws + 458752);
    float* w1t    = (float*)(ws + 459008);
    float* w2t    = (float*)(ws + 606464);
    float* w3t    = (float*)(ws + 901376);

    prep_kernel<<<128, 256, 0, stream>>>(w0, w1, w2, w3, w0t, w1t, w2t, w3t, bias0);
    fps_kernel<<<NB, 1024, 0, stream>>>(xyz, nx_ws, out);
    knn_kernel<<<(NB * NS) / 4, 256, 0, stream>>>(nx_ws, knn_ws);
    conv_kernel<<<NB * NS, 256, 0, stream>>>(feats, nx_ws, knn_ws, w0t, bias0, w1t, w2t, w3t, out);
}